// Round 3
// baseline (288.370 us; speedup 1.0000x reference)
//
#include <hip/hip_runtime.h>

// h: (2,1,1,16,16) fp32 | gi: (2,M,16) | gj: (2,M,16) | theta: (2,M) | out: (2,16,16)
//
// History: R2 VGPR spill 199us. R3/R4 VGPR-loads 48us. R5 barrier dbuf 53us.
// R7 LDS staging DEPTH=3 512blk: 51us. R8 DEPTH=2 1024blk (16 w/CU): 56.6us.
// R9 grid-strided dense front: 53.8us (no change).
// Lesson: delivered BW is 4.1-4.4 B/cyc/CU across ALL structures => per-CU
// outstanding-miss-line queue (~64 lines) x ~950cyc avg latency is the wall.
// Wave count, prefetch depth, and address-front shape are all irrelevant
// once the queue saturates. Only un-replicated datum: R3/R4 plain VGPR
// loads hit 48us (~8% better) => global_load_lds costs extra per line
// (LDS-write-port arbitration on the return path).
// R10 (this): direct per-lane float4 loads to VGPRs, zero LDS staging.
// ml = slot*4+k mapping => theta is a contiguous float4 per lane (no scalar
// dword loads). 18 VMEM instrs / chunk / wave, latency-exposed, pure TLP:
// 1024 blocks, 16 waves/CU (launch_bounds caps VGPR<=128), ~66 unique lines
// per wave in flight at ~64% duty => line queue saturated statistically.
// LDS used only for the 8.4KB final cross-wave fold.

constexpr int MDIM    = 524288;
constexpr int THREADS = 256;
constexpr int BLOCKS  = 1024;             // 4 blocks/CU, 16 waves/CU
constexpr int M_PER_B = MDIM / BLOCKS;    // 512
constexpr int M_PER_W = M_PER_B / 4;      // 128 m per wave
constexpr int CHUNK   = 16;               // m per chunk
constexpr int NCH     = M_PER_W / CHUNK;  // 8 chunks per wave
static_assert(NCH * BLOCKS * 4 * CHUNK == MDIM, "exact tiling");

typedef float f32x2 __attribute__((ext_vector_type(2)));

struct Chunk {
    float4 e[4], f[4], a[4], b[4];
    float4 t0, t1;
};

// Load chunk starting at global row mb (lane's slot folded in by caller).
// 18 x 16B global loads; compiler emits global_load_dwordx4, waits folded.
__device__ __forceinline__ void load_chunk(
    Chunk& ch,
    const float* __restrict__ e_g, const float* __restrict__ f_g,
    const float* __restrict__ a_g, const float* __restrict__ b_g,
    const float* __restrict__ t0_g, const float* __restrict__ t1_g,
    size_t mb, int slot, int i0, int j0)
{
    const size_t mrow = mb + (size_t)slot * 4;   // lane's 4 contiguous m rows
#pragma unroll
    for (int k = 0; k < 4; ++k) {
        ch.e[k] = *(const float4*)(e_g + (mrow + k) * 16 + i0);
        ch.f[k] = *(const float4*)(f_g + (mrow + k) * 16 + i0);
        ch.a[k] = *(const float4*)(a_g + (mrow + k) * 16 + j0);
        ch.b[k] = *(const float4*)(b_g + (mrow + k) * 16 + j0);
    }
    ch.t0 = *(const float4*)(t0_g + mrow);       // contiguous: ml = slot*4+k
    ch.t1 = *(const float4*)(t1_g + mrow);
}

__device__ __forceinline__ void compute_chunk(
    const Chunk& ch, f32x2 (&are)[4][2], f32x2 (&aim)[4][2])
{
    const float tc[4] = {ch.t0.x, ch.t0.y, ch.t0.z, ch.t0.w};
    const float ts[4] = {ch.t1.x, ch.t1.y, ch.t1.z, ch.t1.w};
#pragma unroll
    for (int k = 0; k < 4; ++k) {
        const float c = __cosf(tc[k]);
        const float s = __sinf(ts[k]);
        const f32x2 cc = {c, c}, ss = {s, s};
        const float4 a4 = ch.a[k], b4 = ch.b[k];
        const float4 e4 = ch.e[k], f4 = ch.f[k];
        const f32x2 a01 = {a4.x, a4.y}, a23 = {a4.z, a4.w};
        const f32x2 b01 = {b4.x, b4.y}, b23 = {b4.z, b4.w};
        f32x2 ure[2], uim[2];
        ure[0] = __builtin_elementwise_fma(-b01, ss, a01 * cc);  // a*c - b*s
        ure[1] = __builtin_elementwise_fma(-b23, ss, a23 * cc);
        uim[0] = __builtin_elementwise_fma( b01, cc, a01 * ss);  // a*s + b*c
        uim[1] = __builtin_elementwise_fma( b23, cc, a23 * ss);
        const float ev[4] = {e4.x, e4.y, e4.z, e4.w};
        const float fv[4] = {f4.x, f4.y, f4.z, f4.w};
#pragma unroll
        for (int i = 0; i < 4; ++i) {
            const f32x2 ee = {ev[i], ev[i]};
            const f32x2 ff = {fv[i], fv[i]};
#pragma unroll
            for (int jp = 0; jp < 2; ++jp) {
                are[i][jp] = __builtin_elementwise_fma( ee, ure[jp], are[i][jp]);
                are[i][jp] = __builtin_elementwise_fma(-ff, uim[jp], are[i][jp]);
                aim[i][jp] = __builtin_elementwise_fma( ee, uim[jp], aim[i][jp]);
                aim[i][jp] = __builtin_elementwise_fma( ff, ure[jp], aim[i][jp]);
            }
        }
    }
}

template <bool USE_ATOMIC>
__device__ __forceinline__ void theta_body(
    const float* __restrict__ gi, const float* __restrict__ gj,
    const float* __restrict__ theta, float* __restrict__ dst)
{
    const int t    = threadIdx.x;
    const int wave = t >> 6;
    const int lane = t & 63;
    const int slot = (lane >> 4) & 3;            // lane bits 4,5: m sub-group
    const int tile = lane & 15;
    const int i0   = (tile >> 2) << 2;
    const int j0   = (tile & 3) << 2;
    const size_t m0 = (size_t)(blockIdx.x * 4 + wave) * M_PER_W;

    const float* e_g  = gi;
    const float* f_g  = gi + (size_t)MDIM * 16;
    const float* a_g  = gj;
    const float* b_g  = gj + (size_t)MDIM * 16;
    const float* t0_g = theta;
    const float* t1_g = theta + MDIM;

    f32x2 are[4][2], aim[4][2];
#pragma unroll
    for (int i = 0; i < 4; ++i)
#pragma unroll
        for (int jp = 0; jp < 2; ++jp) { are[i][jp] = {0.f, 0.f}; aim[i][jp] = {0.f, 0.f}; }

    for (int c = 0; c < NCH; ++c) {
        Chunk ch;
        load_chunk(ch, e_g, f_g, a_g, b_g, t0_g, t1_g,
                   m0 + (size_t)c * CHUNK, slot, i0, j0);
        compute_chunk(ch, are, aim);
    }

    // Unpack packed accumulators: j = jp*2 + half.
    float sre[4][4], sim[4][4];
#pragma unroll
    for (int i = 0; i < 4; ++i)
#pragma unroll
        for (int jp = 0; jp < 2; ++jp) {
            sre[i][jp * 2]     = are[i][jp].x;  sre[i][jp * 2 + 1] = are[i][jp].y;
            sim[i][jp * 2]     = aim[i][jp].x;  sim[i][jp * 2 + 1] = aim[i][jp].y;
        }

    // Fold the 4 m-slots (lane bits 4,5).
#pragma unroll
    for (int i = 0; i < 4; ++i)
#pragma unroll
        for (int j = 0; j < 4; ++j) {
            sre[i][j] += __shfl_xor(sre[i][j], 16);
            sre[i][j] += __shfl_xor(sre[i][j], 32);
            sim[i][j] += __shfl_xor(sim[i][j], 16);
            sim[i][j] += __shfl_xor(sim[i][j], 32);
        }

    // Fold the 4 waves via LDS (reduction only; 8448 B).
    __shared__ float red[4][16][33];
    if (lane < 16) {
#pragma unroll
        for (int i = 0; i < 4; ++i)
#pragma unroll
            for (int j = 0; j < 4; ++j) {
                red[wave][lane][i * 4 + j]      = sre[i][j];
                red[wave][lane][16 + i * 4 + j] = sim[i][j];
            }
    }
    __syncthreads();

#pragma unroll
    for (int k = 0; k < 2; ++k) {
        const int idx = t * 2 + k;
        const int tl  = idx >> 5;
        const int v   = idx & 31;
        const float sum = red[0][tl][v] + red[1][tl][v] + red[2][tl][v] + red[3][tl][v];
        const int ii  = ((tl >> 2) << 2) + ((v & 15) >> 2);
        const int jj  = ((tl & 3) << 2) + (v & 3);
        const int off = ((v & 16) ? 256 : 0) + ii * 16 + jj;
        if (USE_ATOMIC) atomicAdd(dst + off, sum);
        else            dst[blockIdx.x * 512 + off] = sum;
    }
}

__global__ __launch_bounds__(THREADS, 4) void theta_main_ws(
    const float* __restrict__ gi, const float* __restrict__ gj,
    const float* __restrict__ theta, float* __restrict__ partial)
{
    theta_body<false>(gi, gj, theta, partial);
}

__global__ __launch_bounds__(THREADS, 4) void theta_main_atomic(
    const float* __restrict__ gi, const float* __restrict__ gj,
    const float* __restrict__ theta, float* __restrict__ out)
{
    theta_body<true>(gi, gj, theta, out);
}

// Stage 2: one wave per output element; fold BLOCKS partials + h bias.
__global__ __launch_bounds__(256) void theta_reduce(
    const float* __restrict__ h, const float* __restrict__ partial,
    float* __restrict__ out)
{
    const int w    = (blockIdx.x * 256 + threadIdx.x) >> 6;  // output index 0..511
    const int lane = threadIdx.x & 63;
    float s = 0.f;
#pragma unroll 4
    for (int j = 0; j < BLOCKS / 64; ++j)
        s += partial[(size_t)(j * 64 + lane) * 512 + w];
#pragma unroll
    for (int d = 1; d < 64; d <<= 1) s += __shfl_xor(s, d);
    if (lane == 0) out[w] = h[w] + s;
}

__global__ void theta_init(const float* __restrict__ h, float* __restrict__ out) {
    int k = blockIdx.x * blockDim.x + threadIdx.x;
    if (k < 512) out[k] = h[k];
}

extern "C" void kernel_launch(void* const* d_in, const int* in_sizes, int n_in,
                              void* d_out, int out_size, void* d_ws, size_t ws_size,
                              hipStream_t stream) {
    const float* h     = (const float*)d_in[0];
    const float* gi    = (const float*)d_in[1];
    const float* gj    = (const float*)d_in[2];
    const float* theta = (const float*)d_in[3];
    float* out = (float*)d_out;

    const size_t need = (size_t)BLOCKS * 512 * sizeof(float);  // 2 MB of partials
    if (ws_size >= need) {
        float* partial = (float*)d_ws;
        theta_main_ws<<<BLOCKS, THREADS, 0, stream>>>(gi, gj, theta, partial);
        theta_reduce<<<128, 256, 0, stream>>>(h, partial, out);
    } else {
        theta_init<<<2, 256, 0, stream>>>(h, out);
        theta_main_atomic<<<BLOCKS, THREADS, 0, stream>>>(gi, gj, theta, out);
    }
}

// Round 4
// 276.435 us; speedup vs baseline: 1.0432x; 1.0432x over previous
//
#include <hip/hip_runtime.h>

// h: (2,1,1,16,16) fp32 | gi: (2,M,16) | gj: (2,M,16) | theta: (2,M) | out: (2,16,16)
//
// History: R2 VGPR spill 199us. R3/R4 VGPR-loads 48us (best ever). R5 dbuf
// 53us. R7 LDS staging DEPTH=3: 51us. R8 16 w/CU: 56.6us. R9 grid-strided
// dense front: 53.8us. R10 VGPR-load retry: 173us SPILL (launch_bounds(,4)
// forced 128-VGPR cap < ~130 live => wholesale scratch demotion; WRITE_SIZE
// 182MB, VGPR_Count 56 = everything in scratch). Test invalid.
// Lessons so far: delivered BW pinned at 4.1-4.4 B/cyc/CU for every LDS
// variant regardless of waves/depth/address-front; R3/R4 plain-VGPR loads
// are the only ~8%-better datum (4.5 B/cyc). Theory: global_load_lds pays
// extra per line on the return path (LDS-write arbitration).
// R11 (this): valid VGPR-load test. NO min-wave launch bound (allocator
// free to ~256 VGPR, 2 waves/SIMD, 8 waves/CU — R8 proved more is useless).
// Named ping-pong register buffers (macros, fully unrolled, static indices
// only), loads for chunk c+1 issued BEFORE computing chunk c => ~18 x 1KB
// coalesced loads per wave permanently in flight. 512 blocks = 2 blocks/CU
// exact residency. LDS only for the 8.4KB final fold.

constexpr int MDIM    = 524288;
constexpr int THREADS = 256;
constexpr int BLOCKS  = 512;              // 2 blocks/CU (VGPR-pinned)
constexpr int M_PER_B = MDIM / BLOCKS;    // 1024
constexpr int M_PER_W = M_PER_B / 4;      // 256 m per wave
constexpr int CHUNK   = 16;               // m per chunk
constexpr int NCH     = M_PER_W / CHUNK;  // 16 chunks per wave
static_assert((NCH & 1) == 0, "ping-pong needs even chunk count");

typedef float f32x2 __attribute__((ext_vector_type(2)));

__device__ __forceinline__ void compute16(
    const float4 (&e)[4], const float4 (&f)[4],
    const float4 (&a)[4], const float4 (&b)[4],
    const float4 t0, const float4 t1,
    f32x2 (&are)[4][2], f32x2 (&aim)[4][2])
{
    const float tc[4] = {t0.x, t0.y, t0.z, t0.w};
    const float ts[4] = {t1.x, t1.y, t1.z, t1.w};
#pragma unroll
    for (int k = 0; k < 4; ++k) {
        const float c = __cosf(tc[k]);
        const float s = __sinf(ts[k]);
        const f32x2 cc = {c, c}, ss = {s, s};
        const f32x2 a01 = {a[k].x, a[k].y}, a23 = {a[k].z, a[k].w};
        const f32x2 b01 = {b[k].x, b[k].y}, b23 = {b[k].z, b[k].w};
        f32x2 ure[2], uim[2];
        ure[0] = __builtin_elementwise_fma(-b01, ss, a01 * cc);  // a*c - b*s
        ure[1] = __builtin_elementwise_fma(-b23, ss, a23 * cc);
        uim[0] = __builtin_elementwise_fma( b01, cc, a01 * ss);  // a*s + b*c
        uim[1] = __builtin_elementwise_fma( b23, cc, a23 * ss);
        const float ev[4] = {e[k].x, e[k].y, e[k].z, e[k].w};
        const float fv[4] = {f[k].x, f[k].y, f[k].z, f[k].w};
#pragma unroll
        for (int i = 0; i < 4; ++i) {
            const f32x2 ee = {ev[i], ev[i]};
            const f32x2 ff = {fv[i], fv[i]};
#pragma unroll
            for (int jp = 0; jp < 2; ++jp) {
                are[i][jp] = __builtin_elementwise_fma( ee, ure[jp], are[i][jp]);
                are[i][jp] = __builtin_elementwise_fma(-ff, uim[jp], are[i][jp]);
                aim[i][jp] = __builtin_elementwise_fma( ee, uim[jp], aim[i][jp]);
                aim[i][jp] = __builtin_elementwise_fma( ff, ure[jp], aim[i][jp]);
            }
        }
    }
}

// Issue the 18 loads of one chunk into named register buffer S.
// mrow = chunk base + this lane's 4-row slot; every index static after unroll.
#define LOADC(S, cidx)                                                        \
    {                                                                         \
        const size_t mrow = m0 + (size_t)(cidx) * CHUNK + (size_t)slot * 4;   \
        _Pragma("unroll")                                                     \
        for (int k = 0; k < 4; ++k) {                                         \
            e##S[k] = *(const float4*)(e_g + (mrow + k) * 16 + i0);           \
            f##S[k] = *(const float4*)(f_g + (mrow + k) * 16 + i0);           \
            a##S[k] = *(const float4*)(a_g + (mrow + k) * 16 + j0);           \
            b##S[k] = *(const float4*)(b_g + (mrow + k) * 16 + j0);           \
        }                                                                     \
        t##S##0 = *(const float4*)(t0_g + mrow);                              \
        t##S##1 = *(const float4*)(t1_g + mrow);                              \
    }

template <bool USE_ATOMIC>
__device__ __forceinline__ void theta_body(
    const float* __restrict__ gi, const float* __restrict__ gj,
    const float* __restrict__ theta, float* __restrict__ dst)
{
    const int t    = threadIdx.x;
    const int wave = t >> 6;
    const int lane = t & 63;
    const int slot = (lane >> 4) & 3;            // lane bits 4,5: m sub-group
    const int tile = lane & 15;
    const int i0   = (tile >> 2) << 2;
    const int j0   = (tile & 3) << 2;
    const size_t m0 = (size_t)(blockIdx.x * 4 + wave) * M_PER_W;

    const float* e_g  = gi;
    const float* f_g  = gi + (size_t)MDIM * 16;
    const float* a_g  = gj;
    const float* b_g  = gj + (size_t)MDIM * 16;
    const float* t0_g = theta;
    const float* t1_g = theta + MDIM;

    f32x2 are[4][2], aim[4][2];
#pragma unroll
    for (int i = 0; i < 4; ++i)
#pragma unroll
        for (int jp = 0; jp < 2; ++jp) { are[i][jp] = {0.f, 0.f}; aim[i][jp] = {0.f, 0.f}; }

    float4 eA[4], fA[4], aA[4], bA[4], tA0, tA1;
    float4 eB[4], fB[4], aB[4], bB[4], tB0, tB1;

    LOADC(A, 0);                                  // chunk 0 in flight
#pragma unroll
    for (int c = 0; c < NCH; c += 2) {
        LOADC(B, c + 1);                          // issue c+1 before computing c
        compute16(eA, fA, aA, bA, tA0, tA1, are, aim);
        if (c + 2 < NCH) LOADC(A, c + 2);         // issue c+2 before computing c+1
        compute16(eB, fB, aB, bB, tB0, tB1, are, aim);
    }

    // Unpack packed accumulators: j = jp*2 + half.
    float sre[4][4], sim[4][4];
#pragma unroll
    for (int i = 0; i < 4; ++i)
#pragma unroll
        for (int jp = 0; jp < 2; ++jp) {
            sre[i][jp * 2]     = are[i][jp].x;  sre[i][jp * 2 + 1] = are[i][jp].y;
            sim[i][jp * 2]     = aim[i][jp].x;  sim[i][jp * 2 + 1] = aim[i][jp].y;
        }

    // Fold the 4 m-slots (lane bits 4,5).
#pragma unroll
    for (int i = 0; i < 4; ++i)
#pragma unroll
        for (int j = 0; j < 4; ++j) {
            sre[i][j] += __shfl_xor(sre[i][j], 16);
            sre[i][j] += __shfl_xor(sre[i][j], 32);
            sim[i][j] += __shfl_xor(sim[i][j], 16);
            sim[i][j] += __shfl_xor(sim[i][j], 32);
        }

    // Fold the 4 waves via LDS (reduction only; 8448 B).
    __shared__ float red[4][16][33];
    if (lane < 16) {
#pragma unroll
        for (int i = 0; i < 4; ++i)
#pragma unroll
            for (int j = 0; j < 4; ++j) {
                red[wave][lane][i * 4 + j]      = sre[i][j];
                red[wave][lane][16 + i * 4 + j] = sim[i][j];
            }
    }
    __syncthreads();

#pragma unroll
    for (int k = 0; k < 2; ++k) {
        const int idx = t * 2 + k;
        const int tl  = idx >> 5;
        const int v   = idx & 31;
        const float sum = red[0][tl][v] + red[1][tl][v] + red[2][tl][v] + red[3][tl][v];
        const int ii  = ((tl >> 2) << 2) + ((v & 15) >> 2);
        const int jj  = ((tl & 3) << 2) + (v & 3);
        const int off = ((v & 16) ? 256 : 0) + ii * 16 + jj;
        if (USE_ATOMIC) atomicAdd(dst + off, sum);
        else            dst[blockIdx.x * 512 + off] = sum;
    }
}

__global__ __launch_bounds__(THREADS) void theta_main_ws(
    const float* __restrict__ gi, const float* __restrict__ gj,
    const float* __restrict__ theta, float* __restrict__ partial)
{
    theta_body<false>(gi, gj, theta, partial);
}

__global__ __launch_bounds__(THREADS) void theta_main_atomic(
    const float* __restrict__ gi, const float* __restrict__ gj,
    const float* __restrict__ theta, float* __restrict__ out)
{
    theta_body<true>(gi, gj, theta, out);
}

// Stage 2: one wave per output element; fold BLOCKS partials + h bias.
__global__ __launch_bounds__(256) void theta_reduce(
    const float* __restrict__ h, const float* __restrict__ partial,
    float* __restrict__ out)
{
    const int w    = (blockIdx.x * 256 + threadIdx.x) >> 6;  // output index 0..511
    const int lane = threadIdx.x & 63;
    float s = 0.f;
#pragma unroll 4
    for (int j = 0; j < BLOCKS / 64; ++j)
        s += partial[(size_t)(j * 64 + lane) * 512 + w];
#pragma unroll
    for (int d = 1; d < 64; d <<= 1) s += __shfl_xor(s, d);
    if (lane == 0) out[w] = h[w] + s;
}

__global__ void theta_init(const float* __restrict__ h, float* __restrict__ out) {
    int k = blockIdx.x * blockDim.x + threadIdx.x;
    if (k < 512) out[k] = h[k];
}

extern "C" void kernel_launch(void* const* d_in, const int* in_sizes, int n_in,
                              void* d_out, int out_size, void* d_ws, size_t ws_size,
                              hipStream_t stream) {
    const float* h     = (const float*)d_in[0];
    const float* gi    = (const float*)d_in[1];
    const float* gj    = (const float*)d_in[2];
    const float* theta = (const float*)d_in[3];
    float* out = (float*)d_out;

    const size_t need = (size_t)BLOCKS * 512 * sizeof(float);  // 1 MB of partials
    if (ws_size >= need) {
        float* partial = (float*)d_ws;
        theta_main_ws<<<BLOCKS, THREADS, 0, stream>>>(gi, gj, theta, partial);
        theta_reduce<<<128, 256, 0, stream>>>(h, partial, out);
    } else {
        theta_init<<<2, 256, 0, stream>>>(h, out);
        theta_main_atomic<<<BLOCKS, THREADS, 0, stream>>>(gi, gj, theta, out);
    }
}

// Round 5
// 164.704 us; speedup vs baseline: 1.7508x; 1.6784x over previous
//
#include <hip/hip_runtime.h>

// h: (2,1,1,16,16) fp32 | gi: (2,M,16) | gj: (2,M,16) | theta: (2,M) | out: (2,16,16)
//
// History: R2 spill 199us. R3/R4 VGPR-loads 48us (best ever; 4 waves/SIMD,
// latency-exposed, TLP-hidden). R5 dbuf 53us. R7 LDS DEPTH=3: 51us.
// R8 16 w/CU LDS: 56.6us. R9 grid-strided front: 53.8us.
// R10 VGPR retry + launch_bounds(,4): SPILL (cap 128 < live ~130; VGPR=56,
// WRITE 182MB). R11 VGPR ping-pong, no bounds: SPILL (live ~190 > backend's
// default ~4-wave/EU register target; VGPR=108, WRITE 247MB).
// Lesson: the AMDGPU backend spills to meet its occupancy target rather
// than dropping occupancy — any VGPR-load design must keep live set < 128.
// Ping-pong double-buffering CANNOT fit: 2x72 buffer VGPRs alone break it.
// R12 (this): exact R3/R4 recipe. SINGLE chunk buffer (18 float4 = 72),
// loads inlined in loop body (short live ranges), no min-wave bound, no
// manual prefetch — 16 waves/CU of pure TLP hide latency. live ~110 < 128
// => 4 waves/SIMD, zero spill. 1024 blocks = 4 blocks/CU exact. LDS only
// for the 8.4KB final fold.
// Ceiling model: per-CU miss-line queue (~64 lines x 64B) / ~950cyc avg
// latency = 4.3 B/cyc/CU = ~2.6 TB/s chip. All clean designs land there.

constexpr int MDIM    = 524288;
constexpr int THREADS = 256;
constexpr int BLOCKS  = 1024;             // 4 blocks/CU at <=128 VGPR
constexpr int M_PER_B = MDIM / BLOCKS;    // 512
constexpr int M_PER_W = M_PER_B / 4;      // 128 m per wave
constexpr int CHUNK   = 16;               // m per chunk
constexpr int NCH     = M_PER_W / CHUNK;  // 8 chunks per wave
static_assert(NCH * BLOCKS * 4 * CHUNK == MDIM, "exact tiling");

typedef float f32x2 __attribute__((ext_vector_type(2)));

template <bool USE_ATOMIC>
__device__ __forceinline__ void theta_body(
    const float* __restrict__ gi, const float* __restrict__ gj,
    const float* __restrict__ theta, float* __restrict__ dst)
{
    const int t    = threadIdx.x;
    const int wave = t >> 6;
    const int lane = t & 63;
    const int slot = (lane >> 4) & 3;            // lane bits 4,5: m sub-group
    const int tile = lane & 15;
    const int i0   = (tile >> 2) << 2;
    const int j0   = (tile & 3) << 2;
    const size_t m0 = (size_t)(blockIdx.x * 4 + wave) * M_PER_W;

    // Per-lane stream pointers with the lane's row/col offset folded in.
    // Row stride 64B; chunk stride 1KB — compiler folds row deltas into
    // 13-bit imm offsets, one VGPR address pair per stream.
    const float* e_p  = gi + (m0 + (size_t)slot * 4) * 16 + i0;
    const float* f_p  = e_p + (size_t)MDIM * 16;
    const float* a_p  = gj + (m0 + (size_t)slot * 4) * 16 + j0;
    const float* b_p  = a_p + (size_t)MDIM * 16;
    const float* t0_p = theta + m0 + (size_t)slot * 4;
    const float* t1_p = t0_p + MDIM;

    f32x2 are[4][2], aim[4][2];
#pragma unroll
    for (int i = 0; i < 4; ++i)
#pragma unroll
        for (int jp = 0; jp < 2; ++jp) { are[i][jp] = {0.f, 0.f}; aim[i][jp] = {0.f, 0.f}; }

    for (int c = 0; c < NCH; ++c) {
        // ---- 18 x 16B loads for this chunk (single buffer, short-lived) ----
        float4 e4[4], f4[4], a4[4], b4[4];
#pragma unroll
        for (int k = 0; k < 4; ++k) {
            e4[k] = *(const float4*)(e_p + k * 16);
            f4[k] = *(const float4*)(f_p + k * 16);
            a4[k] = *(const float4*)(a_p + k * 16);
            b4[k] = *(const float4*)(b_p + k * 16);
        }
        const float4 t0v = *(const float4*)t0_p;
        const float4 t1v = *(const float4*)t1_p;
        e_p += CHUNK * 16; f_p += CHUNK * 16;
        a_p += CHUNK * 16; b_p += CHUNK * 16;
        t0_p += CHUNK;     t1_p += CHUNK;

        // ---- compute ----
        const float tc[4] = {t0v.x, t0v.y, t0v.z, t0v.w};
        const float ts[4] = {t1v.x, t1v.y, t1v.z, t1v.w};
#pragma unroll
        for (int k = 0; k < 4; ++k) {
            const float cv = __cosf(tc[k]);
            const float sv = __sinf(ts[k]);
            const f32x2 cc = {cv, cv}, ss = {sv, sv};
            const f32x2 a01 = {a4[k].x, a4[k].y}, a23 = {a4[k].z, a4[k].w};
            const f32x2 b01 = {b4[k].x, b4[k].y}, b23 = {b4[k].z, b4[k].w};
            f32x2 ure[2], uim[2];
            ure[0] = __builtin_elementwise_fma(-b01, ss, a01 * cc);  // a*c - b*s
            ure[1] = __builtin_elementwise_fma(-b23, ss, a23 * cc);
            uim[0] = __builtin_elementwise_fma( b01, cc, a01 * ss);  // a*s + b*c
            uim[1] = __builtin_elementwise_fma( b23, cc, a23 * ss);
            const float ev[4] = {e4[k].x, e4[k].y, e4[k].z, e4[k].w};
            const float fv[4] = {f4[k].x, f4[k].y, f4[k].z, f4[k].w};
#pragma unroll
            for (int i = 0; i < 4; ++i) {
                const f32x2 ee = {ev[i], ev[i]};
                const f32x2 ff = {fv[i], fv[i]};
#pragma unroll
                for (int jp = 0; jp < 2; ++jp) {
                    are[i][jp] = __builtin_elementwise_fma( ee, ure[jp], are[i][jp]);
                    are[i][jp] = __builtin_elementwise_fma(-ff, uim[jp], are[i][jp]);
                    aim[i][jp] = __builtin_elementwise_fma( ee, uim[jp], aim[i][jp]);
                    aim[i][jp] = __builtin_elementwise_fma( ff, ure[jp], aim[i][jp]);
                }
            }
        }
    }

    // Unpack packed accumulators: j = jp*2 + half.
    float sre[4][4], sim[4][4];
#pragma unroll
    for (int i = 0; i < 4; ++i)
#pragma unroll
        for (int jp = 0; jp < 2; ++jp) {
            sre[i][jp * 2]     = are[i][jp].x;  sre[i][jp * 2 + 1] = are[i][jp].y;
            sim[i][jp * 2]     = aim[i][jp].x;  sim[i][jp * 2 + 1] = aim[i][jp].y;
        }

    // Fold the 4 m-slots (lane bits 4,5).
#pragma unroll
    for (int i = 0; i < 4; ++i)
#pragma unroll
        for (int j = 0; j < 4; ++j) {
            sre[i][j] += __shfl_xor(sre[i][j], 16);
            sre[i][j] += __shfl_xor(sre[i][j], 32);
            sim[i][j] += __shfl_xor(sim[i][j], 16);
            sim[i][j] += __shfl_xor(sim[i][j], 32);
        }

    // Fold the 4 waves via LDS (reduction only; 8448 B).
    __shared__ float red[4][16][33];
    if (lane < 16) {
#pragma unroll
        for (int i = 0; i < 4; ++i)
#pragma unroll
            for (int j = 0; j < 4; ++j) {
                red[wave][lane][i * 4 + j]      = sre[i][j];
                red[wave][lane][16 + i * 4 + j] = sim[i][j];
            }
    }
    __syncthreads();

#pragma unroll
    for (int k = 0; k < 2; ++k) {
        const int idx = t * 2 + k;
        const int tl  = idx >> 5;
        const int v   = idx & 31;
        const float sum = red[0][tl][v] + red[1][tl][v] + red[2][tl][v] + red[3][tl][v];
        const int ii  = ((tl >> 2) << 2) + ((v & 15) >> 2);
        const int jj  = ((tl & 3) << 2) + (v & 3);
        const int off = ((v & 16) ? 256 : 0) + ii * 16 + jj;
        if (USE_ATOMIC) atomicAdd(dst + off, sum);
        else            dst[blockIdx.x * 512 + off] = sum;
    }
}

__global__ __launch_bounds__(THREADS) void theta_main_ws(
    const float* __restrict__ gi, const float* __restrict__ gj,
    const float* __restrict__ theta, float* __restrict__ partial)
{
    theta_body<false>(gi, gj, theta, partial);
}

__global__ __launch_bounds__(THREADS) void theta_main_atomic(
    const float* __restrict__ gi, const float* __restrict__ gj,
    const float* __restrict__ theta, float* __restrict__ out)
{
    theta_body<true>(gi, gj, theta, out);
}

// Stage 2: one wave per output element; fold BLOCKS partials + h bias.
__global__ __launch_bounds__(256) void theta_reduce(
    const float* __restrict__ h, const float* __restrict__ partial,
    float* __restrict__ out)
{
    const int w    = (blockIdx.x * 256 + threadIdx.x) >> 6;  // output index 0..511
    const int lane = threadIdx.x & 63;
    float s = 0.f;
#pragma unroll 4
    for (int j = 0; j < BLOCKS / 64; ++j)
        s += partial[(size_t)(j * 64 + lane) * 512 + w];
#pragma unroll
    for (int d = 1; d < 64; d <<= 1) s += __shfl_xor(s, d);
    if (lane == 0) out[w] = h[w] + s;
}

__global__ void theta_init(const float* __restrict__ h, float* __restrict__ out) {
    int k = blockIdx.x * blockDim.x + threadIdx.x;
    if (k < 512) out[k] = h[k];
}

extern "C" void kernel_launch(void* const* d_in, const int* in_sizes, int n_in,
                              void* d_out, int out_size, void* d_ws, size_t ws_size,
                              hipStream_t stream) {
    const float* h     = (const float*)d_in[0];
    const float* gi    = (const float*)d_in[1];
    const float* gj    = (const float*)d_in[2];
    const float* theta = (const float*)d_in[3];
    float* out = (float*)d_out;

    const size_t need = (size_t)BLOCKS * 512 * sizeof(float);  // 2 MB of partials
    if (ws_size >= need) {
        float* partial = (float*)d_ws;
        theta_main_ws<<<BLOCKS, THREADS, 0, stream>>>(gi, gj, theta, partial);
        theta_reduce<<<128, 256, 0, stream>>>(h, partial, out);
    } else {
        theta_init<<<2, 256, 0, stream>>>(h, out);
        theta_main_atomic<<<BLOCKS, THREADS, 0, stream>>>(gi, gj, theta, out);
    }
}

// Round 7
// 162.824 us; speedup vs baseline: 1.7711x; 1.0115x over previous
//
#include <hip/hip_runtime.h>

// h: (2,1,1,16,16) fp32 | gi: (2,M,16) | gj: (2,M,16) | theta: (2,M) | out: (2,16,16)
//
// History: R3/R4 "48us" never reproduced. Clean designs all plateau 51-57us:
// R7 LDS DEPTH=3 51us | R8 16w/CU 56.6 | R9 grid-strided front 53.8 |
// R12 clean VGPR single-buffer 51.5 (VGPR=52, no spill). R10/R11 spilled
// (backend spills to meet occupancy target; keep live set < 128).
// R13 = this design; bench infra failed twice (no counters, no compile err;
// audit found no hang/fault hazard: vmcnt math, barriers, bounds all OK;
// prior rounds showed 900-1400s infra stalls) => RESUBMIT unchanged.
// Plateau = 4.2 B/cyc/CU delivered. BUT copy ubench = 10.2 B/cyc/CU on this
// chip => not a HW cap. Model: BW/CU = MSHR_lines x 64B / avg_latency;
// latency is PATTERN-dependent. All prior designs: each wave walks 6 streams
// 2MB apart => ~50 scattered 1-4KB islands per CU => row thrash, ~950cyc.
// Copy kernel: few contiguous windows, 16 consecutive lines per instr,
// ~400cyc. R9 densified the GLOBAL front but kept 6 streams/wave => null.
// R14 (this): STREAM-PER-WAVE staging. wave0 stages e(+t0), wave1 f(+t1),
// wave2 a, wave3 b — each stage instr is a full-wave 1KB-contiguous
// global_load_lds (16 consecutive lines, copy-shaped). Chunk=64m, DEPTH=3,
// counted PER-WAVE vmcnt + s_barrier (loads never drained at a barrier —
// the R5 mistake). LDS read map ml=wave*4+slot+16k => adjacent slots on
// opposite bank halves => 2-way conflict (free, m136).

constexpr int MDIM    = 524288;
constexpr int THREADS = 256;
constexpr int BLOCKS  = 512;              // 2 blocks/CU (LDS 50688B each)
constexpr int M_PER_B = MDIM / BLOCKS;    // 1024 m per block
constexpr int CHUNK   = 64;               // m per chunk (block-wide)
constexpr int NCH     = M_PER_B / CHUNK;  // 16 chunks
constexpr int DEPTH   = 3;
static_assert(NCH * BLOCKS * CHUNK == MDIM, "exact tiling");
static_assert(NCH >= DEPTH, "pipeline fill");

// Per-buffer float offsets: e[1024] f[1024] a[1024] b[1024] t0[64] t1[64]
constexpr int E_OFF = 0, F_OFF = 1024, A_OFF = 2048, B_OFF = 3072;
constexpr int T0_OFF = 4096, T1_OFF = 4160;
constexpr int BUF_F  = 4224;
constexpr int SMEM_F = DEPTH * BUF_F;     // 12672 floats = 50688 B
static_assert(SMEM_F * sizeof(float) <= 65536, "LDS < 64 KiB");

typedef float f32x2 __attribute__((ext_vector_type(2)));

#define AS1 __attribute__((address_space(1)))
#define AS3 __attribute__((address_space(3)))

__device__ __forceinline__ void cp16(const float* g, float* l) {
    __builtin_amdgcn_global_load_lds((const AS1 void*)g, (AS3 void*)l, 16, 0, 0);
}
__device__ __forceinline__ void cp4(const float* g, float* l) {
    __builtin_amdgcn_global_load_lds((const AS1 void*)g, (AS3 void*)l, 4, 0, 0);
}

#define WAITV(n) asm volatile("s_waitcnt vmcnt(" #n ")" ::: "memory")

// Stage chunk p of THIS WAVE'S stream into buffer `buf`.
// Waves 0,1: 5 VMEM instrs; waves 2,3: 4. Each cp16 = 64 lanes x 16B
// contiguous = 1 KB = 16 consecutive lines (copy-shaped burst).
__device__ __forceinline__ void stage(
    float* buf, const float* src, const float* tsrc,
    int soff, int toff, int p, int lane)
{
    const float* s = src + (size_t)p * (CHUNK * 16) + lane * 4;
    float* d = buf + soff;
#pragma unroll
    for (int q = 0; q < 4; ++q)
        cp16(s + q * 256, d + q * 256);
    if (tsrc)   // wave-uniform branch
        cp4(tsrc + (size_t)p * CHUNK + lane, buf + toff);
}

__device__ __forceinline__ void compute_chunk(
    const float* buf, int wave, int slot, int i0, int j0,
    f32x2 (&are)[4][2], f32x2 (&aim)[4][2])
{
#pragma unroll
    for (int k = 0; k < 4; ++k) {
        const int ml = wave * 4 + slot + 16 * k;   // adjacent slots: bank halves
        const float4 e4 = *(const float4*)(buf + E_OFF + ml * 16 + i0);
        const float4 f4 = *(const float4*)(buf + F_OFF + ml * 16 + i0);
        const float4 a4 = *(const float4*)(buf + A_OFF + ml * 16 + j0);
        const float4 b4 = *(const float4*)(buf + B_OFF + ml * 16 + j0);
        const float cv = __cosf(buf[T0_OFF + ml]);
        const float sv = __sinf(buf[T1_OFF + ml]);
        const f32x2 cc = {cv, cv}, ss = {sv, sv};
        const f32x2 a01 = {a4.x, a4.y}, a23 = {a4.z, a4.w};
        const f32x2 b01 = {b4.x, b4.y}, b23 = {b4.z, b4.w};
        f32x2 ure[2], uim[2];
        ure[0] = __builtin_elementwise_fma(-b01, ss, a01 * cc);  // a*c - b*s
        ure[1] = __builtin_elementwise_fma(-b23, ss, a23 * cc);
        uim[0] = __builtin_elementwise_fma( b01, cc, a01 * ss);  // a*s + b*c
        uim[1] = __builtin_elementwise_fma( b23, cc, a23 * ss);
        const float ev[4] = {e4.x, e4.y, e4.z, e4.w};
        const float fv[4] = {f4.x, f4.y, f4.z, f4.w};
#pragma unroll
        for (int i = 0; i < 4; ++i) {
            const f32x2 ee = {ev[i], ev[i]};
            const f32x2 ff = {fv[i], fv[i]};
#pragma unroll
            for (int jp = 0; jp < 2; ++jp) {
                are[i][jp] = __builtin_elementwise_fma( ee, ure[jp], are[i][jp]);
                are[i][jp] = __builtin_elementwise_fma(-ff, uim[jp], are[i][jp]);
                aim[i][jp] = __builtin_elementwise_fma( ee, uim[jp], aim[i][jp]);
                aim[i][jp] = __builtin_elementwise_fma( ff, ure[jp], aim[i][jp]);
            }
        }
    }
}

template <bool USE_ATOMIC>
__device__ __forceinline__ void theta_body(
    const float* __restrict__ gi, const float* __restrict__ gj,
    const float* __restrict__ theta, float* __restrict__ dst)
{
    __shared__ float smem[SMEM_F];
    const int t    = threadIdx.x;
    const int wave = t >> 6;
    const int lane = t & 63;
    const int slot = (lane >> 4) & 3;
    const int tile = lane & 15;
    const int i0   = (tile >> 2) << 2;
    const int j0   = (tile & 3) << 2;
    const size_t mB = (size_t)blockIdx.x * M_PER_B;

    // This wave's stream (stream-per-wave specialization).
    const float* src;  const float* tsrc = nullptr;
    int soff, toff = 0;
    if      (wave == 0) { src = gi + mB * 16;                     soff = E_OFF; tsrc = theta + mB;        toff = T0_OFF; }
    else if (wave == 1) { src = gi + (size_t)MDIM * 16 + mB * 16; soff = F_OFF; tsrc = theta + MDIM + mB; toff = T1_OFF; }
    else if (wave == 2) { src = gj + mB * 16;                     soff = A_OFF; }
    else                { src = gj + (size_t)MDIM * 16 + mB * 16; soff = B_OFF; }

    f32x2 are[4][2], aim[4][2];
#pragma unroll
    for (int i = 0; i < 4; ++i)
#pragma unroll
        for (int jp = 0; jp < 2; ++jp) { are[i][jp] = {0.f, 0.f}; aim[i][jp] = {0.f, 0.f}; }

    // Fill: 3 chunks in flight (per wave: 3W instrs, W = 5|5|4|4).
    stage(smem + 0 * BUF_F, src, tsrc, soff, toff, 0, lane);
    stage(smem + 1 * BUF_F, src, tsrc, soff, toff, 1, lane);
    stage(smem + 2 * BUF_F, src, tsrc, soff, toff, 2, lane);

    int cb = 0;
    for (int c = 0; c < NCH; ++c) {
        // Wait for OWN chunk-c loads (retire-in-order): outstanding beyond c
        // is min(2, NCH-1-c) chunks x W. Literal vmcnt per wave role.
        if (c <= NCH - 3) { if (wave < 2) WAITV(10); else WAITV(8); }
        else if (c == NCH - 2) { if (wave < 2) WAITV(5); else WAITV(4); }
        else { WAITV(0); }
        __syncthreads();                          // all 4 streams of chunk c landed
        compute_chunk(smem + cb * BUF_F, wave, slot, i0, j0, are, aim);
        __syncthreads();                          // everyone done reading buf cb
        if (c + 3 < NCH)
            stage(smem + cb * BUF_F, src, tsrc, soff, toff, c + 3, lane);
        cb = (cb == DEPTH - 1) ? 0 : cb + 1;
    }

    // Unpack packed accumulators: j = jp*2 + half.
    float sre[4][4], sim[4][4];
#pragma unroll
    for (int i = 0; i < 4; ++i)
#pragma unroll
        for (int jp = 0; jp < 2; ++jp) {
            sre[i][jp * 2]     = are[i][jp].x;  sre[i][jp * 2 + 1] = are[i][jp].y;
            sim[i][jp * 2]     = aim[i][jp].x;  sim[i][jp * 2 + 1] = aim[i][jp].y;
        }

    // Fold the 4 m-slots (lane bits 4,5).
#pragma unroll
    for (int i = 0; i < 4; ++i)
#pragma unroll
        for (int j = 0; j < 4; ++j) {
            sre[i][j] += __shfl_xor(sre[i][j], 16);
            sre[i][j] += __shfl_xor(sre[i][j], 32);
            sim[i][j] += __shfl_xor(sim[i][j], 16);
            sim[i][j] += __shfl_xor(sim[i][j], 32);
        }

    // Fold the 4 waves via LDS (smem fully consumed; barrier makes reuse safe).
    __syncthreads();
    float (*red)[16][33] = (float (*)[16][33])smem;
    if (lane < 16) {
#pragma unroll
        for (int i = 0; i < 4; ++i)
#pragma unroll
            for (int j = 0; j < 4; ++j) {
                red[wave][lane][i * 4 + j]      = sre[i][j];
                red[wave][lane][16 + i * 4 + j] = sim[i][j];
            }
    }
    __syncthreads();

#pragma unroll
    for (int k = 0; k < 2; ++k) {
        const int idx = t * 2 + k;
        const int tl  = idx >> 5;
        const int v   = idx & 31;
        const float sum = red[0][tl][v] + red[1][tl][v] + red[2][tl][v] + red[3][tl][v];
        const int ii  = ((tl >> 2) << 2) + ((v & 15) >> 2);
        const int jj  = ((tl & 3) << 2) + (v & 3);
        const int off = ((v & 16) ? 256 : 0) + ii * 16 + jj;
        if (USE_ATOMIC) atomicAdd(dst + off, sum);
        else            dst[blockIdx.x * 512 + off] = sum;
    }
}

__global__ __launch_bounds__(THREADS) void theta_main_ws(
    const float* __restrict__ gi, const float* __restrict__ gj,
    const float* __restrict__ theta, float* __restrict__ partial)
{
    theta_body<false>(gi, gj, theta, partial);
}

__global__ __launch_bounds__(THREADS) void theta_main_atomic(
    const float* __restrict__ gi, const float* __restrict__ gj,
    const float* __restrict__ theta, float* __restrict__ out)
{
    theta_body<true>(gi, gj, theta, out);
}

// Stage 2: one wave per output element; fold BLOCKS partials + h bias.
__global__ __launch_bounds__(256) void theta_reduce(
    const float* __restrict__ h, const float* __restrict__ partial,
    float* __restrict__ out)
{
    const int w    = (blockIdx.x * 256 + threadIdx.x) >> 6;  // output index 0..511
    const int lane = threadIdx.x & 63;
    float s = 0.f;
#pragma unroll 4
    for (int j = 0; j < BLOCKS / 64; ++j)
        s += partial[(size_t)(j * 64 + lane) * 512 + w];
#pragma unroll
    for (int d = 1; d < 64; d <<= 1) s += __shfl_xor(s, d);
    if (lane == 0) out[w] = h[w] + s;
}

__global__ void theta_init(const float* __restrict__ h, float* __restrict__ out) {
    int k = blockIdx.x * blockDim.x + threadIdx.x;
    if (k < 512) out[k] = h[k];
}

extern "C" void kernel_launch(void* const* d_in, const int* in_sizes, int n_in,
                              void* d_out, int out_size, void* d_ws, size_t ws_size,
                              hipStream_t stream) {
    const float* h     = (const float*)d_in[0];
    const float* gi    = (const float*)d_in[1];
    const float* gj    = (const float*)d_in[2];
    const float* theta = (const float*)d_in[3];
    float* out = (float*)d_out;

    const size_t need = (size_t)BLOCKS * 512 * sizeof(float);  // 1 MB of partials
    if (ws_size >= need) {
        float* partial = (float*)d_ws;
        theta_main_ws<<<BLOCKS, THREADS, 0, stream>>>(gi, gj, theta, partial);
        theta_reduce<<<128, 256, 0, stream>>>(h, partial, out);
    } else {
        theta_init<<<2, 256, 0, stream>>>(h, out);
        theta_main_atomic<<<BLOCKS, THREADS, 0, stream>>>(gi, gj, theta, out);
    }
}